// Round 5
// baseline (1211.833 us; speedup 1.0000x reference)
//
#include <hip/hip_runtime.h>
#include <math.h>

// Problem constants
#define BATCH 32768
#define EMB   2048
#define KDIM  320      // 5*8*8
#define KACT  103      // ceil(0.05*2048)

// GEMM tiling
#define BM 16
#define GTHREADS 512

// Conv batching (== BM so one conv block produces exactly one A-tile)
#define CIMG 16

// Radix histogram row stride (16B-aligned, != 0 mod 32 banks)
#define HSTRIDE 260
// Two histogram copies to halve same-address atomic serialization
#define HCOPY 2

// ---------------------------------------------------------------------------
// Kernel 0: transpose fc_w (2048 x 320) -> WT (320 x 2048).
// ---------------------------------------------------------------------------
__global__ __launch_bounds__(256) void transpose_w_kernel(const float* __restrict__ W,
                                                          float* __restrict__ WT) {
  __shared__ float tile[32][33];
  const int k0 = blockIdx.x * 32;
  const int n0 = blockIdx.y * 32;
  const int tx = threadIdx.x;
  const int ty = threadIdx.y;
  for (int i = ty; i < 32; i += 8)
    tile[i][tx] = W[(size_t)(n0 + i) * KDIM + k0 + tx];
  __syncthreads();
  for (int i = ty; i < 32; i += 8)
    WT[(size_t)(k0 + i) * EMB + n0 + tx] = tile[tx][i];
}

// ---------------------------------------------------------------------------
// Kernel 1: conv3x3(valid) + batchnorm + relu + maxpool3x3 stride3 (valid).
// (unchanged from round 4 — correct, residual-neutral)
// 16 images per 512-thread block; tile-major contiguous A-tile output.
// ---------------------------------------------------------------------------
__global__ __launch_bounds__(512) void conv_pool_kernel(const float* __restrict__ x,
                                                        const float* __restrict__ cw,
                                                        const float* __restrict__ gamma,
                                                        const float* __restrict__ beta,
                                                        const float* __restrict__ mean,
                                                        const float* __restrict__ var,
                                                        float* __restrict__ Ht) {
#pragma clang fp contract(off)
  __shared__ float xs[CIMG * 784];       // 50 KB
  __shared__ float hs[KDIM * 17];        // k-major staging, stride 17
  __shared__ float wv[45];
  __shared__ float inv_s[5], mu_s[5], be_s[5];
  const int t  = threadIdx.x;
  const int b0 = blockIdx.x * CIMG;

  {
    const float4* src = (const float4*)(x + (size_t)b0 * 784);
    float4* dst = (float4*)xs;
    for (int i = t; i < CIMG * 196; i += 512) dst[i] = src[i];
  }
  if (t < 45) wv[t] = cw[t];
  if (t < 5) {
    inv_s[t] = gamma[t] / sqrtf(var[t] + 1e-5f);  // IEEE div & sqrt
    mu_s[t] = mean[t];
    be_s[t] = beta[t];
  }
  __syncthreads();

  const int i0   = t >> 6;
  const int lane = t & 63;
  const int py = lane >> 3;
  const int px = lane & 7;

  for (int ii = 0; ii < 2; ++ii) {
    const int img = i0 * 2 + ii;
    const float* xb = xs + img * 784;

    float xr[5][5];
#pragma unroll
    for (int i = 0; i < 5; ++i)
#pragma unroll
      for (int j = 0; j < 5; ++j)
        xr[i][j] = xb[(3 * py + i) * 28 + 3 * px + j];

#pragma unroll
    for (int c = 0; c < 5; ++c) {
      float wr[9];
#pragma unroll
      for (int i = 0; i < 9; ++i) wr[i] = wv[c * 9 + i];
      const float inv = inv_s[c], mu = mu_s[c], be = be_s[c];
      float mx = -__builtin_huge_valf();
#pragma unroll
      for (int ry = 0; ry < 3; ++ry)
#pragma unroll
        for (int rx = 0; rx < 3; ++rx) {
          float s = 0.0f;
#pragma unroll
          for (int di = 0; di < 3; ++di)
#pragma unroll
            for (int dj = 0; dj < 3; ++dj)
              s = __builtin_fmaf(xr[ry + di][rx + dj], wr[di * 3 + dj], s);
          float t1 = s - mu;
          float t2 = t1 * inv;
          float t3 = t2 + be;
          mx = fmaxf(mx, t3);
        }
      hs[(c * 64 + lane) * 17 + img] = fmaxf(mx, 0.0f);
    }
  }
  __syncthreads();

  float* dst = Ht + (size_t)blockIdx.x * (KDIM * CIMG);
  for (int i = t; i < KDIM * CIMG; i += 512) {
    const int k = i >> 4;
    const int img = i & 15;
    dst[i] = hs[k * 17 + img];
  }
}

// ---------------------------------------------------------------------------
// Kernel 2: fused GEMM + per-row rank-103 threshold + binary write.
// k-loop: round-3 structure (direct uniform loads -> s_load, NO register
// rotate, compiler schedules within the unrolled k4 body), tile-major A so
// scalar lines are sequential (K$-line reuse between consecutive k).
// Epilogue: acc mapped to ordered-uint ONCE in place; 4-pass radix-256 with
// TWO histogram copies (waves 0-3 / 4-7) merged at scan time.
// FMA chain per element: serial ascending k — unchanged from passing rounds.
// ---------------------------------------------------------------------------
__global__ __launch_bounds__(GTHREADS) void gemm_topk_kernel(const float* __restrict__ Ht,
                                                             const float* __restrict__ WT,
                                                             float* __restrict__ out) {
  __shared__ unsigned histo[HCOPY * BM * HSTRIDE];   // ~33.3 KB
  __shared__ unsigned prefix_s[BM];
  __shared__ unsigned rank_s[BM];

  const int t    = threadIdx.x;
  const int lane = t & 63;
  const int w    = t >> 6;               // wave 0..7
  const int m0   = blockIdx.x * BM;
  const int nt   = t * 4;

  if (t < BM) { prefix_s[t] = 0u; rank_s[t] = KACT; }

  float acc[BM][4];
#pragma unroll
  for (int m = 0; m < BM; ++m)
#pragma unroll
    for (int j = 0; j < 4; ++j) acc[m][j] = 0.0f;

  const float* Ap = Ht + (size_t)blockIdx.x * (KDIM * BM);  // A(k,m)=Ap[k*16+m]
  const float* wp = WT + nt;
  float4 nb0 = *(const float4*)(wp + 0 * EMB);
  float4 nb1 = *(const float4*)(wp + 1 * EMB);
  float4 nb2 = *(const float4*)(wp + 2 * EMB);
  float4 nb3 = *(const float4*)(wp + 3 * EMB);

  for (int k4 = 0; k4 < KDIM / 4; ++k4) {
    const float4 b0 = nb0, b1 = nb1, b2 = nb2, b3 = nb3;
    if (k4 + 1 < KDIM / 4) {  // uniform branch; prefetch next 4 B-rows
      const float* wn = wp + (size_t)(k4 + 1) * 4 * EMB;
      nb0 = *(const float4*)(wn + 0 * EMB);
      nb1 = *(const float4*)(wn + 1 * EMB);
      nb2 = *(const float4*)(wn + 2 * EMB);
      nb3 = *(const float4*)(wn + 3 * EMB);
    }
#pragma unroll
    for (int kk = 0; kk < 4; ++kk) {
      const float* ak = Ap + (size_t)(4 * k4 + kk) * BM;
      float av[BM];
#pragma unroll
      for (int m = 0; m < BM; ++m) av[m] = ak[m];   // uniform -> s_load_dwordx16
      const float4 bb = (kk == 0) ? b0 : (kk == 1) ? b1 : (kk == 2) ? b2 : b3;
#pragma unroll
      for (int m = 0; m < BM; ++m) {
        acc[m][0] = __builtin_fmaf(av[m], bb.x, acc[m][0]);
        acc[m][1] = __builtin_fmaf(av[m], bb.y, acc[m][1]);
        acc[m][2] = __builtin_fmaf(av[m], bb.z, acc[m][2]);
        acc[m][3] = __builtin_fmaf(av[m], bb.w, acc[m][3]);
      }
    }
  }

  // Map to order-preserving uint ONCE (acc dead after this; regs coalesce)
  unsigned ua[BM][4];
#pragma unroll
  for (int m = 0; m < BM; ++m)
#pragma unroll
    for (int j = 0; j < 4; ++j) {
      unsigned u = __float_as_uint(acc[m][j]);
      ua[m][j] = (u & 0x80000000u) ? ~u : (u | 0x80000000u);
    }

  unsigned* hc = histo + (w >> 2) * (BM * HSTRIDE);  // this wave's histo copy

  __syncthreads();  // prefix_s/rank_s init visible before select

  // ---- radix-256 select of the KACT-th largest per row ----
  for (int pass = 0; pass < 4; ++pass) {
    const int shift = 24 - pass * 8;
    for (int i = t; i < HCOPY * BM * HSTRIDE; i += GTHREADS) histo[i] = 0u;
    unsigned pref[BM];
#pragma unroll
    for (int m = 0; m < BM; ++m) pref[m] = prefix_s[m];
    __syncthreads();
#pragma unroll
    for (int m = 0; m < BM; ++m) {
#pragma unroll
      for (int j = 0; j < 4; ++j) {
        const unsigned u = ua[m][j];
        const bool in = (pass == 0) || ((u >> (shift + 8)) == pref[m]);
        if (in) atomicAdd(&hc[m * HSTRIDE + ((u >> shift) & 255u)], 1u);
      }
    }
    __syncthreads();
    // Scan: wave w handles rows 2w, 2w+1; merge both histo copies.
    for (int rr = 0; rr < 2; ++rr) {
      const int m = w * 2 + rr;
      const unsigned rank = rank_s[m];
      const uint4 c0 = *(const uint4*)(histo + m * HSTRIDE + lane * 4);
      const uint4 c1 = *(const uint4*)(histo + BM * HSTRIDE + m * HSTRIDE + lane * 4);
      uint4 c;
      c.x = c0.x + c1.x; c.y = c0.y + c1.y; c.z = c0.z + c1.z; c.w = c0.w + c1.w;
      const unsigned s = c.x + c.y + c.z + c.w;
      unsigned suf = s;
#pragma unroll
      for (int off = 1; off < 64; off <<= 1) {
        const unsigned o = __shfl_down(suf, off);
        if (lane + off < 64) suf += o;
      }
      const unsigned above = suf - s;  // counts in bins > 4*lane+3
      if (above < rank && rank <= suf) {  // exactly one lane hits
        unsigned bin, newr;
        if (above + c.w >= rank)                    { bin = lane * 4 + 3; newr = rank - above; }
        else if (above + c.w + c.z >= rank)         { bin = lane * 4 + 2; newr = rank - above - c.w; }
        else if (above + c.w + c.z + c.y >= rank)   { bin = lane * 4 + 1; newr = rank - above - c.w - c.z; }
        else                                        { bin = lane * 4 + 0; newr = rank - above - c.w - c.z - c.y; }
        prefix_s[m] = (prefix_s[m] << 8) | bin;
        rank_s[m] = newr;
      }
    }
    __syncthreads();
  }

  unsigned thr[BM];
#pragma unroll
  for (int m = 0; m < BM; ++m) thr[m] = prefix_s[m];

#pragma unroll
  for (int m = 0; m < BM; ++m) {
    float4 o;
    float* op = (float*)&o;
#pragma unroll
    for (int j = 0; j < 4; ++j)
      op[j] = (ua[m][j] >= thr[m]) ? 1.0f : 0.0f;  // same tie semantics as z >= topv[:,-1]
    *(float4*)(out + (size_t)(m0 + m) * EMB + nt) = o;
  }
}

// ---------------------------------------------------------------------------
extern "C" void kernel_launch(void* const* d_in, const int* in_sizes, int n_in,
                              void* d_out, int out_size, void* d_ws, size_t ws_size,
                              hipStream_t stream) {
  const float* x      = (const float*)d_in[0];
  const float* conv_w = (const float*)d_in[1];
  const float* gamma  = (const float*)d_in[2];
  const float* beta   = (const float*)d_in[3];
  const float* mean   = (const float*)d_in[4];
  const float* var    = (const float*)d_in[5];
  const float* fc_w   = (const float*)d_in[6];
  float* out = (float*)d_out;

  // workspace: Ht tile-major (2048 tiles x 320 x 16 f32 = 40 MB) | WT (320x2048)
  float* Ht = (float*)d_ws;
  float* WT = (float*)d_ws + (size_t)KDIM * BATCH;

  transpose_w_kernel<<<dim3(KDIM / 32, EMB / 32), dim3(32, 8), 0, stream>>>(fc_w, WT);
  conv_pool_kernel<<<BATCH / CIMG, 512, 0, stream>>>(x, conv_w, gamma, beta, mean, var, Ht);
  gemm_topk_kernel<<<BATCH / BM, GTHREADS, 0, stream>>>(Ht, WT, out);
}

// Round 6
// 978.510 us; speedup vs baseline: 1.2384x; 1.2384x over previous
//
#include <hip/hip_runtime.h>
#include <math.h>

// Problem constants
#define BATCH 32768
#define EMB   2048
#define KDIM  320      // 5*8*8
#define KACT  103      // ceil(0.05*2048)

// GEMM tiling
#define BM 16
#define GTHREADS 512

// Conv batching (== BM so one conv block produces exactly one A-tile)
#define CIMG 16

// Radix histogram row stride (16B-aligned, != 0 mod 32 banks)
#define HSTRIDE 260

// ---------------------------------------------------------------------------
// Kernel 0: transpose fc_w (2048 x 320) -> WT (320 x 2048).
// ---------------------------------------------------------------------------
__global__ __launch_bounds__(256) void transpose_w_kernel(const float* __restrict__ W,
                                                          float* __restrict__ WT) {
  __shared__ float tile[32][33];
  const int k0 = blockIdx.x * 32;
  const int n0 = blockIdx.y * 32;
  const int tx = threadIdx.x;
  const int ty = threadIdx.y;
  for (int i = ty; i < 32; i += 8)
    tile[i][tx] = W[(size_t)(n0 + i) * KDIM + k0 + tx];
  __syncthreads();
  for (int i = ty; i < 32; i += 8)
    WT[(size_t)(k0 + i) * EMB + n0 + tx] = tile[tx][i];
}

// ---------------------------------------------------------------------------
// Kernel 1: conv3x3(valid) + batchnorm + relu + maxpool3x3 stride3 (valid).
// (unchanged — correct, residual-neutral)
// 16 images per 512-thread block; tile-major contiguous A-tile output.
// ---------------------------------------------------------------------------
__global__ __launch_bounds__(512) void conv_pool_kernel(const float* __restrict__ x,
                                                        const float* __restrict__ cw,
                                                        const float* __restrict__ gamma,
                                                        const float* __restrict__ beta,
                                                        const float* __restrict__ mean,
                                                        const float* __restrict__ var,
                                                        float* __restrict__ Ht) {
#pragma clang fp contract(off)
  __shared__ float xs[CIMG * 784];       // 50 KB
  __shared__ float hs[KDIM * 17];        // k-major staging, stride 17
  __shared__ float wv[45];
  __shared__ float inv_s[5], mu_s[5], be_s[5];
  const int t  = threadIdx.x;
  const int b0 = blockIdx.x * CIMG;

  {
    const float4* src = (const float4*)(x + (size_t)b0 * 784);
    float4* dst = (float4*)xs;
    for (int i = t; i < CIMG * 196; i += 512) dst[i] = src[i];
  }
  if (t < 45) wv[t] = cw[t];
  if (t < 5) {
    inv_s[t] = gamma[t] / sqrtf(var[t] + 1e-5f);  // IEEE div & sqrt
    mu_s[t] = mean[t];
    be_s[t] = beta[t];
  }
  __syncthreads();

  const int i0   = t >> 6;
  const int lane = t & 63;
  const int py = lane >> 3;
  const int px = lane & 7;

  for (int ii = 0; ii < 2; ++ii) {
    const int img = i0 * 2 + ii;
    const float* xb = xs + img * 784;

    float xr[5][5];
#pragma unroll
    for (int i = 0; i < 5; ++i)
#pragma unroll
      for (int j = 0; j < 5; ++j)
        xr[i][j] = xb[(3 * py + i) * 28 + 3 * px + j];

#pragma unroll
    for (int c = 0; c < 5; ++c) {
      float wr[9];
#pragma unroll
      for (int i = 0; i < 9; ++i) wr[i] = wv[c * 9 + i];
      const float inv = inv_s[c], mu = mu_s[c], be = be_s[c];
      float mx = -__builtin_huge_valf();
#pragma unroll
      for (int ry = 0; ry < 3; ++ry)
#pragma unroll
        for (int rx = 0; rx < 3; ++rx) {
          float s = 0.0f;
#pragma unroll
          for (int di = 0; di < 3; ++di)
#pragma unroll
            for (int dj = 0; dj < 3; ++dj)
              s = __builtin_fmaf(xr[ry + di][rx + dj], wr[di * 3 + dj], s);
          float t1 = s - mu;
          float t2 = t1 * inv;
          float t3 = t2 + be;
          mx = fmaxf(mx, t3);
        }
      hs[(c * 64 + lane) * 17 + img] = fmaxf(mx, 0.0f);
    }
  }
  __syncthreads();

  float* dst = Ht + (size_t)blockIdx.x * (KDIM * CIMG);
  for (int i = t; i < KDIM * CIMG; i += 512) {
    const int k = i >> 4;
    const int img = i & 15;
    dst[i] = hs[k * 17 + img];
  }
}

// ---------------------------------------------------------------------------
// Kernel 2: fused GEMM + per-row rank-103 threshold + binary write.
// EXACT round-3 structure (the low-VGPR fast variant: on-the-fly uint
// conversion in the radix passes, single histogram) with two deltas:
//  - tile-major A: per-k 64B uniform s_load lines are SEQUENTIAL (K$ reuse)
//  - #pragma unroll 2 on the k4 loop: 8 s_loads batched per 1024 compute
//    cycles, halving exposed scalar-load latency (no HIP-level rotation —
//    that inflated VGPRs in r4/r5 and throttled occupancy).
// FMA chain per element: serial ascending k — unchanged from passing rounds.
// ---------------------------------------------------------------------------
__global__ __launch_bounds__(GTHREADS) void gemm_topk_kernel(const float* __restrict__ Ht,
                                                             const float* __restrict__ WT,
                                                             float* __restrict__ out) {
  __shared__ unsigned histo[BM * HSTRIDE];   // ~16.6 KB
  __shared__ unsigned prefix_s[BM];
  __shared__ unsigned rank_s[BM];

  const int t    = threadIdx.x;
  const int lane = t & 63;
  const int w    = t >> 6;               // wave 0..7
  const int m0   = blockIdx.x * BM;
  const int nt   = t * 4;

  if (t < BM) { prefix_s[t] = 0u; rank_s[t] = KACT; }

  float acc[BM][4];
#pragma unroll
  for (int m = 0; m < BM; ++m)
#pragma unroll
    for (int j = 0; j < 4; ++j) acc[m][j] = 0.0f;

  const float* Ap = Ht + (size_t)blockIdx.x * (KDIM * BM);  // A(k,m)=Ap[k*16+m]
  const float* wp = WT + nt;
  float4 nb0 = *(const float4*)(wp + 0 * EMB);
  float4 nb1 = *(const float4*)(wp + 1 * EMB);
  float4 nb2 = *(const float4*)(wp + 2 * EMB);
  float4 nb3 = *(const float4*)(wp + 3 * EMB);

#pragma unroll 2
  for (int k4 = 0; k4 < KDIM / 4; ++k4) {
    const float4 b0 = nb0, b1 = nb1, b2 = nb2, b3 = nb3;
    if (k4 + 1 < KDIM / 4) {  // uniform branch; prefetch next 4 B-rows
      const float* wn = wp + (size_t)(k4 + 1) * 4 * EMB;
      nb0 = *(const float4*)(wn + 0 * EMB);
      nb1 = *(const float4*)(wn + 1 * EMB);
      nb2 = *(const float4*)(wn + 2 * EMB);
      nb3 = *(const float4*)(wn + 3 * EMB);
    }
#pragma unroll
    for (int kk = 0; kk < 4; ++kk) {
      const float* ak = Ap + (size_t)(4 * k4 + kk) * BM;
      float av[BM];
#pragma unroll
      for (int m = 0; m < BM; ++m) av[m] = ak[m];   // uniform -> s_load_dwordx16
      const float4 bb = (kk == 0) ? b0 : (kk == 1) ? b1 : (kk == 2) ? b2 : b3;
#pragma unroll
      for (int m = 0; m < BM; ++m) {
        acc[m][0] = __builtin_fmaf(av[m], bb.x, acc[m][0]);
        acc[m][1] = __builtin_fmaf(av[m], bb.y, acc[m][1]);
        acc[m][2] = __builtin_fmaf(av[m], bb.z, acc[m][2]);
        acc[m][3] = __builtin_fmaf(av[m], bb.w, acc[m][3]);
      }
    }
  }
  __syncthreads();  // prefix_s/rank_s init visible to all before select

  // ---- radix-256 select of the KACT-th largest per row ----
  for (int pass = 0; pass < 4; ++pass) {
    const int shift = 24 - pass * 8;
    for (int i = t; i < BM * HSTRIDE; i += GTHREADS) histo[i] = 0u;
    unsigned pref[BM];
#pragma unroll
    for (int m = 0; m < BM; ++m) pref[m] = prefix_s[m];
    __syncthreads();
#pragma unroll
    for (int m = 0; m < BM; ++m) {
#pragma unroll
      for (int j = 0; j < 4; ++j) {
        unsigned u = __float_as_uint(acc[m][j]);
        u = (u & 0x80000000u) ? ~u : (u | 0x80000000u);  // ascending order map
        const bool in = (pass == 0) || ((u >> (shift + 8)) == pref[m]);
        if (in) atomicAdd(&histo[m * HSTRIDE + ((u >> shift) & 255u)], 1u);
      }
    }
    __syncthreads();
    // Scan: wave w handles rows 2w, 2w+1. Lane l covers bins [4l,4l+4);
    // higher lane = higher-valued bins. Suffix-sum gives counts-above.
    for (int rr = 0; rr < 2; ++rr) {
      const int m = w * 2 + rr;
      const unsigned rank = rank_s[m];
      const uint4 c = *(const uint4*)(histo + m * HSTRIDE + lane * 4);
      const unsigned s = c.x + c.y + c.z + c.w;
      unsigned suf = s;
#pragma unroll
      for (int off = 1; off < 64; off <<= 1) {
        const unsigned o = __shfl_down(suf, off);
        if (lane + off < 64) suf += o;
      }
      const unsigned above = suf - s;  // counts in bins > 4*lane+3
      if (above < rank && rank <= suf) {  // exactly one lane hits
        unsigned bin, newr;
        if (above + c.w >= rank)                    { bin = lane * 4 + 3; newr = rank - above; }
        else if (above + c.w + c.z >= rank)         { bin = lane * 4 + 2; newr = rank - above - c.w; }
        else if (above + c.w + c.z + c.y >= rank)   { bin = lane * 4 + 1; newr = rank - above - c.w - c.z; }
        else                                        { bin = lane * 4 + 0; newr = rank - above - c.w - c.z - c.y; }
        prefix_s[m] = (prefix_s[m] << 8) | bin;
        rank_s[m] = newr;
      }
    }
    __syncthreads();
  }

  // prefix_s[m] now holds the exact uint-mapped 103rd-largest value
  unsigned thr[BM];
#pragma unroll
  for (int m = 0; m < BM; ++m) thr[m] = prefix_s[m];

#pragma unroll
  for (int m = 0; m < BM; ++m) {
    float4 o;
    float* op = (float*)&o;
#pragma unroll
    for (int j = 0; j < 4; ++j) {
      unsigned u = __float_as_uint(acc[m][j]);
      u = (u & 0x80000000u) ? ~u : (u | 0x80000000u);
      op[j] = (u >= thr[m]) ? 1.0f : 0.0f;  // same tie semantics as z >= topv[:,-1]
    }
    *(float4*)(out + (size_t)(m0 + m) * EMB + nt) = o;
  }
}

// ---------------------------------------------------------------------------
extern "C" void kernel_launch(void* const* d_in, const int* in_sizes, int n_in,
                              void* d_out, int out_size, void* d_ws, size_t ws_size,
                              hipStream_t stream) {
  const float* x      = (const float*)d_in[0];
  const float* conv_w = (const float*)d_in[1];
  const float* gamma  = (const float*)d_in[2];
  const float* beta   = (const float*)d_in[3];
  const float* mean   = (const float*)d_in[4];
  const float* var    = (const float*)d_in[5];
  const float* fc_w   = (const float*)d_in[6];
  float* out = (float*)d_out;

  // workspace: Ht tile-major (2048 tiles x 320 x 16 f32 = 40 MB) | WT (320x2048)
  float* Ht = (float*)d_ws;
  float* WT = (float*)d_ws + (size_t)KDIM * BATCH;

  transpose_w_kernel<<<dim3(KDIM / 32, EMB / 32), dim3(32, 8), 0, stream>>>(fc_w, WT);
  conv_pool_kernel<<<BATCH / CIMG, 512, 0, stream>>>(x, conv_w, gamma, beta, mean, var, Ht);
  gemm_topk_kernel<<<BATCH / BM, GTHREADS, 0, stream>>>(Ht, WT, out);
}

// Round 7
// 824.771 us; speedup vs baseline: 1.4693x; 1.1864x over previous
//
#include <hip/hip_runtime.h>
#include <math.h>

// Problem constants
#define BATCH 32768
#define EMB   2048
#define KDIM  320      // 5*8*8
#define KACT  103      // ceil(0.05*2048)

// GEMM tiling: 1024 threads, 16 rows x 2048 cols per block, 2 cols/thread.
// Rationale (r4/r5/r6 post-mortems): throughput tracks resident waves; the
// only way to 8 waves/SIMD is total regs <= 64 -> acc[16][2] (32) + no
// manual B prefetch. A values live in SGPRs (uniform s_load) and feed
// v_fma_f32 directly, costing zero VGPRs.
#define BM 16
#define GTHREADS 1024

// Conv batching (== BM so one conv block produces exactly one A-tile)
#define CIMG 16

// Radix histogram row stride (16B-aligned, != 0 mod 32 banks)
#define HSTRIDE 260

// ---------------------------------------------------------------------------
// Kernel 0: transpose fc_w (2048 x 320) -> WT (320 x 2048).
// ---------------------------------------------------------------------------
__global__ __launch_bounds__(256) void transpose_w_kernel(const float* __restrict__ W,
                                                          float* __restrict__ WT) {
  __shared__ float tile[32][33];
  const int k0 = blockIdx.x * 32;
  const int n0 = blockIdx.y * 32;
  const int tx = threadIdx.x;
  const int ty = threadIdx.y;
  for (int i = ty; i < 32; i += 8)
    tile[i][tx] = W[(size_t)(n0 + i) * KDIM + k0 + tx];
  __syncthreads();
  for (int i = ty; i < 32; i += 8)
    WT[(size_t)(k0 + i) * EMB + n0 + tx] = tile[tx][i];
}

// ---------------------------------------------------------------------------
// Kernel 1: conv3x3(valid) + batchnorm + relu + maxpool3x3 stride3 (valid).
// (unchanged — correct, residual-neutral)
// 16 images per 512-thread block; tile-major contiguous A-tile output.
// ---------------------------------------------------------------------------
__global__ __launch_bounds__(512) void conv_pool_kernel(const float* __restrict__ x,
                                                        const float* __restrict__ cw,
                                                        const float* __restrict__ gamma,
                                                        const float* __restrict__ beta,
                                                        const float* __restrict__ mean,
                                                        const float* __restrict__ var,
                                                        float* __restrict__ Ht) {
#pragma clang fp contract(off)
  __shared__ float xs[CIMG * 784];       // 50 KB
  __shared__ float hs[KDIM * 17];        // k-major staging, stride 17
  __shared__ float wv[45];
  __shared__ float inv_s[5], mu_s[5], be_s[5];
  const int t  = threadIdx.x;
  const int b0 = blockIdx.x * CIMG;

  {
    const float4* src = (const float4*)(x + (size_t)b0 * 784);
    float4* dst = (float4*)xs;
    for (int i = t; i < CIMG * 196; i += 512) dst[i] = src[i];
  }
  if (t < 45) wv[t] = cw[t];
  if (t < 5) {
    inv_s[t] = gamma[t] / sqrtf(var[t] + 1e-5f);  // IEEE div & sqrt
    mu_s[t] = mean[t];
    be_s[t] = beta[t];
  }
  __syncthreads();

  const int i0   = t >> 6;
  const int lane = t & 63;
  const int py = lane >> 3;
  const int px = lane & 7;

  for (int ii = 0; ii < 2; ++ii) {
    const int img = i0 * 2 + ii;
    const float* xb = xs + img * 784;

    float xr[5][5];
#pragma unroll
    for (int i = 0; i < 5; ++i)
#pragma unroll
      for (int j = 0; j < 5; ++j)
        xr[i][j] = xb[(3 * py + i) * 28 + 3 * px + j];

#pragma unroll
    for (int c = 0; c < 5; ++c) {
      float wr[9];
#pragma unroll
      for (int i = 0; i < 9; ++i) wr[i] = wv[c * 9 + i];
      const float inv = inv_s[c], mu = mu_s[c], be = be_s[c];
      float mx = -__builtin_huge_valf();
#pragma unroll
      for (int ry = 0; ry < 3; ++ry)
#pragma unroll
        for (int rx = 0; rx < 3; ++rx) {
          float s = 0.0f;
#pragma unroll
          for (int di = 0; di < 3; ++di)
#pragma unroll
            for (int dj = 0; dj < 3; ++dj)
              s = __builtin_fmaf(xr[ry + di][rx + dj], wr[di * 3 + dj], s);
          float t1 = s - mu;
          float t2 = t1 * inv;
          float t3 = t2 + be;
          mx = fmaxf(mx, t3);
        }
      hs[(c * 64 + lane) * 17 + img] = fmaxf(mx, 0.0f);
    }
  }
  __syncthreads();

  float* dst = Ht + (size_t)blockIdx.x * (KDIM * CIMG);
  for (int i = t; i < KDIM * CIMG; i += 512) {
    const int k = i >> 4;
    const int img = i & 15;
    dst[i] = hs[k * 17 + img];
  }
}

// ---------------------------------------------------------------------------
// Kernel 2: fused GEMM + per-row rank-103 threshold + binary write.
// 1024 threads, 2 cols/thread (acc[16][2] = 32 VGPRs). Occupancy-first:
// __launch_bounds__(1024, 8) caps total regs at 64 -> 2 blocks/CU
// (8 waves/SIMD), double round-3. A via uniform s_load (SGPR operands,
// sequential 64B lines in tile-major Ht); B via direct L2 float2 loads —
// latency hidden by TLP, no prefetch registers.
// FMA chain per element: serial ascending k — unchanged from passing rounds.
// Top-k: 4-pass radix-256, one row per wave in the scan.
// ---------------------------------------------------------------------------
__global__ __launch_bounds__(GTHREADS, 8) void gemm_topk_kernel(const float* __restrict__ Ht,
                                                                const float* __restrict__ WT,
                                                                float* __restrict__ out) {
  __shared__ unsigned histo[BM * HSTRIDE];   // ~16.6 KB
  __shared__ unsigned prefix_s[BM];
  __shared__ unsigned rank_s[BM];

  const int t    = threadIdx.x;
  const int lane = t & 63;
  const int w    = t >> 6;               // wave 0..15
  const int m0   = blockIdx.x * BM;
  const int nt   = t * 2;                // 2 columns per thread

  if (t < BM) { prefix_s[t] = 0u; rank_s[t] = KACT; }

  float acc[BM][2];
#pragma unroll
  for (int m = 0; m < BM; ++m) {
    acc[m][0] = 0.0f;
    acc[m][1] = 0.0f;
  }

  const float* Ap = Ht + (size_t)blockIdx.x * (KDIM * BM);  // A(k,m)=Ap[k*16+m]
  const float* wp = WT + nt;

#pragma unroll 4
  for (int k = 0; k < KDIM; ++k) {
    const float* ak = Ap + (size_t)k * BM;
    float av[BM];
#pragma unroll
    for (int m = 0; m < BM; ++m) av[m] = ak[m];   // uniform -> s_load (SGPRs)
    const float2 bb = *(const float2*)(wp + (size_t)k * EMB);
#pragma unroll
    for (int m = 0; m < BM; ++m) {
      acc[m][0] = __builtin_fmaf(av[m], bb.x, acc[m][0]);
      acc[m][1] = __builtin_fmaf(av[m], bb.y, acc[m][1]);
    }
  }
  __syncthreads();  // prefix_s/rank_s init visible to all before select

  // ---- radix-256 select of the KACT-th largest per row ----
  for (int pass = 0; pass < 4; ++pass) {
    const int shift = 24 - pass * 8;
    for (int i = t; i < BM * HSTRIDE; i += GTHREADS) histo[i] = 0u;
    unsigned pref[BM];
#pragma unroll
    for (int m = 0; m < BM; ++m) pref[m] = prefix_s[m];
    __syncthreads();
#pragma unroll
    for (int m = 0; m < BM; ++m) {
#pragma unroll
      for (int j = 0; j < 2; ++j) {
        unsigned u = __float_as_uint(acc[m][j]);
        u = (u & 0x80000000u) ? ~u : (u | 0x80000000u);  // ascending order map
        const bool in = (pass == 0) || ((u >> (shift + 8)) == pref[m]);
        if (in) atomicAdd(&histo[m * HSTRIDE + ((u >> shift) & 255u)], 1u);
      }
    }
    __syncthreads();
    // Scan: wave w handles row w (16 waves <-> 16 rows). Lane l covers bins
    // [4l,4l+4); higher lane = higher-valued bins. Suffix-sum = counts-above.
    {
      const int m = w;
      const unsigned rank = rank_s[m];
      const uint4 c = *(const uint4*)(histo + m * HSTRIDE + lane * 4);
      const unsigned s = c.x + c.y + c.z + c.w;
      unsigned suf = s;
#pragma unroll
      for (int off = 1; off < 64; off <<= 1) {
        const unsigned o = __shfl_down(suf, off);
        if (lane + off < 64) suf += o;
      }
      const unsigned above = suf - s;  // counts in bins > 4*lane+3
      if (above < rank && rank <= suf) {  // exactly one lane hits
        unsigned bin, newr;
        if (above + c.w >= rank)                    { bin = lane * 4 + 3; newr = rank - above; }
        else if (above + c.w + c.z >= rank)         { bin = lane * 4 + 2; newr = rank - above - c.w; }
        else if (above + c.w + c.z + c.y >= rank)   { bin = lane * 4 + 1; newr = rank - above - c.w - c.z; }
        else                                        { bin = lane * 4 + 0; newr = rank - above - c.w - c.z - c.y; }
        prefix_s[m] = (prefix_s[m] << 8) | bin;
        rank_s[m] = newr;
      }
    }
    __syncthreads();
  }

  // prefix_s[m] now holds the exact uint-mapped 103rd-largest value
  unsigned thr[BM];
#pragma unroll
  for (int m = 0; m < BM; ++m) thr[m] = prefix_s[m];

#pragma unroll
  for (int m = 0; m < BM; ++m) {
    float2 o;
#pragma unroll
    for (int j = 0; j < 2; ++j) {
      unsigned u = __float_as_uint(acc[m][j]);
      u = (u & 0x80000000u) ? ~u : (u | 0x80000000u);
      ((float*)&o)[j] = (u >= thr[m]) ? 1.0f : 0.0f;  // tie semantics: z >= topv[:,-1]
    }
    *(float2*)(out + (size_t)(m0 + m) * EMB + nt) = o;
  }
}

// ---------------------------------------------------------------------------
extern "C" void kernel_launch(void* const* d_in, const int* in_sizes, int n_in,
                              void* d_out, int out_size, void* d_ws, size_t ws_size,
                              hipStream_t stream) {
  const float* x      = (const float*)d_in[0];
  const float* conv_w = (const float*)d_in[1];
  const float* gamma  = (const float*)d_in[2];
  const float* beta   = (const float*)d_in[3];
  const float* mean   = (const float*)d_in[4];
  const float* var    = (const float*)d_in[5];
  const float* fc_w   = (const float*)d_in[6];
  float* out = (float*)d_out;

  // workspace: Ht tile-major (2048 tiles x 320 x 16 f32 = 40 MB) | WT (320x2048)
  float* Ht = (float*)d_ws;
  float* WT = (float*)d_ws + (size_t)KDIM * BATCH;

  transpose_w_kernel<<<dim3(KDIM / 32, EMB / 32), dim3(32, 8), 0, stream>>>(fc_w, WT);
  conv_pool_kernel<<<BATCH / CIMG, 512, 0, stream>>>(x, conv_w, gamma, beta, mean, var, Ht);
  gemm_topk_kernel<<<BATCH / BM, GTHREADS, 0, stream>>>(Ht, WT, out);
}